// Round 4
// baseline (225.617 us; speedup 1.0000x reference)
//
#include <hip/hip_runtime.h>
#include <math.h>

static constexpr int B_ = 4;
static constexpr int L_ = 1024;
static constexpr int S_ = 1024;
static constexpr int DMODEL = 512;
static constexpr int NH = 8;
static constexpr int DH = 64;
static constexpr int NBH = 32;   // B_*NH

typedef __attribute__((ext_vector_type(8))) short s8;      // 8 bf16 (4 VGPRs)
typedef __attribute__((ext_vector_type(4))) float floatx4; // MFMA accumulator

__device__ __forceinline__ short f2bf(float f) {           // RNE f32->bf16
  unsigned u = __float_as_uint(f);
  return (short)((u + 0x7fffu + ((u >> 16) & 1u)) >> 16);
}
__device__ __forceinline__ float bf2f(short s) {
  return __uint_as_float(((unsigned)(unsigned short)s) << 16);
}

// ---------------------------------------------------------------------------
// Convert queries/keys/values (f32) -> contiguous bf16 segments in ws.
// ---------------------------------------------------------------------------
__global__ __launch_bounds__(256)
void cvt_inputs_kernel(const float* __restrict__ q, const float* __restrict__ k,
                       const float* __restrict__ v, short* __restrict__ dst) {
  const int i = blockIdx.x * 256 + threadIdx.x;          // 0..786431
  const int arr = i >> 18;                               // 0..2 (uniform per block)
  const int off = (i & 262143) << 3;
  const float* src = (arr == 0) ? q : (arr == 1) ? k : v;
  const float4 f0 = *(const float4*)(src + off);
  const float4 f1 = *(const float4*)(src + off + 4);
  s8 o;
  o[0] = f2bf(f0.x); o[1] = f2bf(f0.y); o[2] = f2bf(f0.z); o[3] = f2bf(f0.w);
  o[4] = f2bf(f1.x); o[5] = f2bf(f1.y); o[6] = f2bf(f1.z); o[7] = f2bf(f1.w);
  *(s8*)(dst + (size_t)arr * 2097152 + off) = o;
}

// ---------------------------------------------------------------------------
// Transpose + cvt the 4 weight matrices: W (512x512 f32, [k][n]) -> WT bf16 [n][k]
// ---------------------------------------------------------------------------
__global__ __launch_bounds__(256)
void wtrans_kernel(const float* __restrict__ Wq, const float* __restrict__ Wk,
                   const float* __restrict__ Wv, const float* __restrict__ Wo,
                   short* __restrict__ WT) {
  __shared__ float t[32][33];
  const int z = blockIdx.z;
  const float* W = (z == 0) ? Wq : (z == 1) ? Wk : (z == 2) ? Wv : Wo;
  short* dst = WT + (size_t)z * 262144;
  const int k0 = blockIdx.y * 32, n0 = blockIdx.x * 32;
  const int row = threadIdx.x >> 3;          // 0..31
  const int c4 = (threadIdx.x & 7) << 2;     // 0,4,..28
  const float4 f = *(const float4*)(W + (size_t)(k0 + row) * 512 + n0 + c4);
  t[row][c4 + 0] = f.x; t[row][c4 + 1] = f.y; t[row][c4 + 2] = f.z; t[row][c4 + 3] = f.w;
  __syncthreads();
#pragma unroll
  for (int j = 0; j < 4; ++j)
    dst[(size_t)(n0 + row) * 512 + k0 + c4 + j] = f2bf(t[c4 + j][row]);
}

// ---------------------------------------------------------------------------
// MFMA projection GEMM: C = A(M x K, bf16 row-major) @ WT^T (WT is N x K bf16).
// MODE 0: store bf16 (B,H,L,D)   MODE 2: f32 row-major
// MODE 3: dual store bf16 vT (B,H,D,S) at C and vS (B,H,S,D) at C2
// ---------------------------------------------------------------------------
template<int MODE>
__global__ __launch_bounds__(256)
void proj_mfma_kernel(const short* __restrict__ A, const short* __restrict__ WT,
                      void* __restrict__ C, short* __restrict__ C2, int K) {
  const int tid = threadIdx.x;
  const int lane = tid & 63, w = tid >> 6;
  const int wm = w >> 1, wn = w & 1;
  const int m0 = blockIdx.y * 64, n0 = blockIdx.x * 64;
  const int kl = (lane >> 4) << 3;            // 0,8,16,24
  const int rA = m0 + wm * 32 + (lane & 15);
  const int rB = n0 + wn * 32 + (lane & 15);
  const short* pA = A + (size_t)rA * K + kl;
  const short* pB = WT + (size_t)rB * K + kl;
  const size_t f16K = (size_t)16 * K;
  floatx4 acc00 = {0,0,0,0}, acc01 = {0,0,0,0}, acc10 = {0,0,0,0}, acc11 = {0,0,0,0};
  for (int k = 0; k < K; k += 32) {
    const s8 a0 = *(const s8*)(pA + k);
    const s8 a1 = *(const s8*)(pA + f16K + k);
    const s8 b0 = *(const s8*)(pB + k);
    const s8 b1 = *(const s8*)(pB + f16K + k);
    acc00 = __builtin_amdgcn_mfma_f32_16x16x32_bf16(a0, b0, acc00, 0, 0, 0);
    acc01 = __builtin_amdgcn_mfma_f32_16x16x32_bf16(a0, b1, acc01, 0, 0, 0);
    acc10 = __builtin_amdgcn_mfma_f32_16x16x32_bf16(a1, b0, acc10, 0, 0, 0);
    acc11 = __builtin_amdgcn_mfma_f32_16x16x32_bf16(a1, b1, acc11, 0, 0, 0);
  }
  const int crow = (lane >> 4) << 2;          // 0,4,8,12
  const int ccol = lane & 15;
#pragma unroll
  for (int fm = 0; fm < 2; ++fm)
#pragma unroll
    for (int fn = 0; fn < 2; ++fn) {
      const floatx4 acc = (fm == 0) ? ((fn == 0) ? acc00 : acc01)
                                    : ((fn == 0) ? acc10 : acc11);
      const int col = n0 + wn * 32 + fn * 16 + ccol;
#pragma unroll
      for (int r = 0; r < 4; ++r) {
        const int row = m0 + wm * 32 + fm * 16 + crow + r;
        if (MODE == 0) {
          const int b = row >> 10, l = row & 1023, h = col >> 6, d = col & 63;
          ((short*)C)[((size_t)((b * NH + h) * L_ + l)) * DH + d] = f2bf(acc[r]);
        } else if (MODE == 3) {
          const int b = row >> 10, s = row & 1023, h = col >> 6, d = col & 63;
          const short val = f2bf(acc[r]);
          ((short*)C)[((size_t)((b * NH + h) * DH + d)) * S_ + s] = val;   // vT
          C2[((size_t)((b * NH + h) * S_ + s)) * DH + d] = val;            // vS
        } else {
          ((float*)C)[(size_t)row * DMODEL + col] = acc[r];
        }
      }
    }
}

// ---------------------------------------------------------------------------
// Scores via MFMA: Sc[bh][l][s] = 0.125 * sum_d q[bh,l,d] * k[bh,s,d]  (f32 out)
// ---------------------------------------------------------------------------
__global__ __launch_bounds__(256)
void scores_mfma_kernel(const short* __restrict__ qbf, const short* __restrict__ kbf,
                        float* __restrict__ Sc) {
  const int tid = threadIdx.x;
  const int lane = tid & 63, w = tid >> 6;
  const int wm = w >> 1, wn = w & 1;
  const int m0 = blockIdx.y * 64, n0 = blockIdx.x * 64;
  const int bh = blockIdx.z;
  const int kl = (lane >> 4) << 3;
  const short* pA = qbf + (size_t)bh * L_ * DH + (size_t)(m0 + wm * 32 + (lane & 15)) * DH + kl;
  const short* pB = kbf + (size_t)bh * S_ * DH + (size_t)(n0 + wn * 32 + (lane & 15)) * DH + kl;
  floatx4 acc00 = {0,0,0,0}, acc01 = {0,0,0,0}, acc10 = {0,0,0,0}, acc11 = {0,0,0,0};
#pragma unroll
  for (int k = 0; k < DH; k += 32) {
    const s8 a0 = *(const s8*)(pA + k);
    const s8 a1 = *(const s8*)(pA + 16 * DH + k);
    const s8 b0 = *(const s8*)(pB + k);
    const s8 b1 = *(const s8*)(pB + 16 * DH + k);
    acc00 = __builtin_amdgcn_mfma_f32_16x16x32_bf16(a0, b0, acc00, 0, 0, 0);
    acc01 = __builtin_amdgcn_mfma_f32_16x16x32_bf16(a0, b1, acc01, 0, 0, 0);
    acc10 = __builtin_amdgcn_mfma_f32_16x16x32_bf16(a1, b0, acc10, 0, 0, 0);
    acc11 = __builtin_amdgcn_mfma_f32_16x16x32_bf16(a1, b1, acc11, 0, 0, 0);
  }
  float* Cp = Sc + (size_t)bh * L_ * S_;
  const int crow = (lane >> 4) << 2;
  const int ccol = lane & 15;
#pragma unroll
  for (int fm = 0; fm < 2; ++fm)
#pragma unroll
    for (int fn = 0; fn < 2; ++fn) {
      const floatx4 acc = (fm == 0) ? ((fn == 0) ? acc00 : acc01)
                                    : ((fn == 0) ? acc10 : acc11);
      const int col = n0 + wn * 32 + fn * 16 + ccol;
#pragma unroll
      for (int r = 0; r < 4; ++r) {
        const int row = m0 + wm * 32 + fm * 16 + crow + r;
        Cp[(size_t)row * S_ + col] = acc[r] * 0.125f;
      }
    }
}

// ---------------------------------------------------------------------------
// path_mean[i][j] = (1/32) * sum_bh Sc[bh][i][m1] * Sc[bh][m2][j]  (tiled gather)
// ---------------------------------------------------------------------------
__global__ __launch_bounds__(256)
void path_mean_kernel(const float* __restrict__ Sc, float* __restrict__ pm) {
  __shared__ float As[32][36];
  __shared__ float Bs[32][36];
  const int orig = blockIdx.x;
  const int wgid = (orig & 7) * 128 + (orig >> 3);
  const int i0 = (wgid >> 5) << 5;
  const int j0 = (wgid & 31) << 5;
  const int c0 = (2 * i0 + j0) / 3;
  const int c0_al = c0 & ~3;
  const int r0 = (i0 + 2 * j0) / 3;
  const int tid = threadIdx.x;
  const int row_s = tid >> 3;
  const int c4 = tid & 7;
  const int ti = tid >> 3;
  const int tj = tid & 7;
  const int gi = i0 + ti;
  int aoff[4], boff[4];
#pragma unroll
  for (int b = 0; b < 4; ++b) {
    const int gj = j0 + 4 * tj + b;
    const int m1 = (2 * gi + gj) / 3;
    const int m2 = (gi + 2 * gj) / 3;
    aoff[b] = ti * 36 + (m1 - c0_al);
    boff[b] = (m2 - r0) * 36 + (4 * tj + b);
  }
  const int gcA = c0_al + 4 * c4;
  int gcA2 = c0_al + 32; if (gcA2 > 1020) gcA2 = 1020;
  const float* pA  = Sc + (size_t)(i0 + row_s) * S_ + gcA;
  const float* pA2 = Sc + (size_t)(i0 + (tid & 31)) * S_ + gcA2;
  const float* pB  = Sc + (size_t)(r0 + row_s) * S_ + j0 + 4 * c4;
  const float* As0 = &As[0][0];
  const float* Bs0 = &Bs[0][0];
  float acc[4] = {0.f, 0.f, 0.f, 0.f};
  for (int z = 0; z < NBH; ++z) {
    const size_t zo = (size_t)z * (L_ * S_);
    const float4 av = *(const float4*)(pA + zo);
    const float4 bv = *(const float4*)(pB + zo);
    float4 av2;
    if (tid < 32) av2 = *(const float4*)(pA2 + zo);
    __syncthreads();
    *(float4*)&As[row_s][4 * c4] = av;
    if (tid < 32) *(float4*)&As[tid][32] = av2;
    *(float4*)&Bs[row_s][4 * c4] = bv;
    __syncthreads();
#pragma unroll
    for (int b = 0; b < 4; ++b)
      acc[b] = fmaf(As0[aoff[b]], Bs0[boff[b]], acc[b]);
  }
  float4 o = make_float4(acc[0] * (1.f / 32.f), acc[1] * (1.f / 32.f),
                         acc[2] * (1.f / 32.f), acc[3] * (1.f / 32.f));
  *(float4*)&pm[(size_t)gi * S_ + j0 + 4 * tj] = o;
}

// ---------------------------------------------------------------------------
// pm_stats: per row i of pm (far positions only, |i-j|>3):
//   pmmax[i] = max_far pm[i,j]; pmsum[i] = sum_far exp(pm - pmmax)
//   E[i,j] = bf16(exp(pm[i,j] - pmmax[i]))  (0 on the band)
// One wave per row.
// ---------------------------------------------------------------------------
__global__ __launch_bounds__(256)
void pm_stats_kernel(const float* __restrict__ pm, short* __restrict__ E,
                     float* __restrict__ pmmax, float* __restrict__ pmsum) {
  const int wid = threadIdx.x >> 6, lane = threadIdx.x & 63;
  const int i = blockIdx.x * 4 + wid;
  const float* row = pm + (size_t)i * S_;
  const int j0 = lane << 4;
  float v[16];
#pragma unroll
  for (int c = 0; c < 4; ++c) {
    const float4 f = *(const float4*)(row + j0 + c * 4);
    v[c * 4 + 0] = f.x; v[c * 4 + 1] = f.y; v[c * 4 + 2] = f.z; v[c * 4 + 3] = f.w;
  }
  float mx = -1e30f;
#pragma unroll
  for (int u = 0; u < 16; ++u) {
    const int d = i - (j0 + u);
    const bool far = (d > 3) || (d < -3);
    if (far) mx = fmaxf(mx, v[u]);
  }
#pragma unroll
  for (int off = 32; off >= 1; off >>= 1) mx = fmaxf(mx, __shfl_xor(mx, off));
  float sum = 0.f;
  short e[16];
#pragma unroll
  for (int u = 0; u < 16; ++u) {
    const int d = i - (j0 + u);
    const bool far = (d > 3) || (d < -3);
    const float ev = far ? __expf(v[u] - mx) : 0.f;
    sum += ev;
    e[u] = f2bf(ev);
  }
#pragma unroll
  for (int off = 32; off >= 1; off >>= 1) sum += __shfl_xor(sum, off);
  s8 o0, o1;
#pragma unroll
  for (int u = 0; u < 8; ++u) { o0[u] = e[u]; o1[u] = e[8 + u]; }
  short* Erow = E + (size_t)i * S_ + j0;
  *(s8*)Erow = o0;
  *(s8*)(Erow + 8) = o1;
  if (lane == 0) { pmmax[i] = mx; pmsum[i] = sum; }
}

// ---------------------------------------------------------------------------
// attn_write: one wave per (bh, i) row. In-place: Sc row currently holds raw
// scores; band values (|i-j|<=3) are read first (in-lane), then the full attn
// row is written: far = c*E[i,:], band = exp(s-m)/sum. Also emits c and the 7
// band attn values for the EV epilogue.
// ---------------------------------------------------------------------------
__global__ __launch_bounds__(256)
void attn_write_kernel(float* __restrict__ Sc, const short* __restrict__ E,
                       const float* __restrict__ pmmax, const float* __restrict__ pmsum,
                       float* __restrict__ cvec, float* __restrict__ band) {
  const int wid = threadIdx.x >> 6, lane = threadIdx.x & 63;
  const int i = blockIdx.x * 4 + wid;
  const int bh = blockIdx.y;
  float* row = Sc + ((size_t)bh * L_ + i) * S_;

  // band score for lanes 0..6 (invalid -> -1e30)
  const int j_u = i - 3 + lane;
  float s_u = -1e30f;
  if (lane < 7 && j_u >= 0 && j_u < S_) s_u = row[j_u];

  // wave-reduce band max / expsum (lanes >=7 contribute -1e30 -> exp 0)
  float bm = s_u;
#pragma unroll
  for (int off = 32; off >= 1; off >>= 1) bm = fmaxf(bm, __shfl_xor(bm, off));
  const float pmx = pmmax[i];
  const float m = fmaxf(pmx, bm);
  const float bexp = __expf(s_u - m);
  float bsum = bexp;
#pragma unroll
  for (int off = 32; off >= 1; off >>= 1) bsum += __shfl_xor(bsum, off);
  const float cpm = __expf(pmx - m);
  const float inv = 1.f / (bsum + pmsum[i] * cpm);
  const float c = cpm * inv;

  if (lane == 0) cvec[bh * L_ + i] = c;
  if (lane < 8) band[((size_t)(bh * L_ + i)) << 3 | lane] = __expf(s_u - m) * inv;

  // write the attn row: far = c * E, band recomputed from own-chunk raw score
  const short* Erow = E + (size_t)i * S_;
  const int j0 = lane << 4;
  const s8 e0 = *(const s8*)(Erow + j0);
  const s8 e1 = *(const s8*)(Erow + j0 + 8);
  float outv[16];
#pragma unroll
  for (int u = 0; u < 8; ++u) {
    outv[u]     = bf2f(e0[u]) * c;
    outv[8 + u] = bf2f(e1[u]) * c;
  }
#pragma unroll
  for (int t = 0; t < 16; ++t) {
    const int j = j0 + t;
    const int d = j - i;
    if (d >= -3 && d <= 3)                     // band col in own chunk:
      outv[t] = __expf(row[j] - m) * inv;      // load precedes stores below
  }
#pragma unroll
  for (int c4 = 0; c4 < 4; ++c4)
    *(float4*)(row + j0 + c4 * 4) =
        make_float4(outv[c4 * 4], outv[c4 * 4 + 1], outv[c4 * 4 + 2], outv[c4 * 4 + 3]);
}

// ---------------------------------------------------------------------------
// EV GEMM + epilogue: out1[b,l,h*64+d] = c(bh,l)*(E @ V_bh)[l,d] + band corr.
// A = E (bf16, shared across bh, L2-resident), B = vT (B,H,D,S).
// ---------------------------------------------------------------------------
__global__ __launch_bounds__(256)
void ev_kernel(const short* __restrict__ E, const short* __restrict__ vT,
               const short* __restrict__ vS, const float* __restrict__ cvec,
               const float* __restrict__ band, short* __restrict__ out1) {
  const int tid = threadIdx.x;
  const int lane = tid & 63, w = tid >> 6;
  const int wm = w >> 1, wn = w & 1;
  const int m0 = blockIdx.x * 64;
  const int bh = blockIdx.y;
  const int b = bh >> 3, h = bh & 7;
  const int kl = (lane >> 4) << 3;
  const short* pA = E + (size_t)(m0 + wm * 32 + (lane & 15)) * S_ + kl;
  const short* pB = vT + (size_t)bh * DH * S_ + (size_t)(wn * 32 + (lane & 15)) * S_ + kl;
  floatx4 acc00 = {0,0,0,0}, acc01 = {0,0,0,0}, acc10 = {0,0,0,0}, acc11 = {0,0,0,0};
  for (int k = 0; k < S_; k += 32) {
    const s8 a0 = *(const s8*)(pA + k);
    const s8 a1 = *(const s8*)(pA + 16 * S_ + k);
    const s8 b0 = *(const s8*)(pB + k);
    const s8 b1 = *(const s8*)(pB + 16 * S_ + k);
    acc00 = __builtin_amdgcn_mfma_f32_16x16x32_bf16(a0, b0, acc00, 0, 0, 0);
    acc01 = __builtin_amdgcn_mfma_f32_16x16x32_bf16(a0, b1, acc01, 0, 0, 0);
    acc10 = __builtin_amdgcn_mfma_f32_16x16x32_bf16(a1, b0, acc10, 0, 0, 0);
    acc11 = __builtin_amdgcn_mfma_f32_16x16x32_bf16(a1, b1, acc11, 0, 0, 0);
  }
  const int crow = (lane >> 4) << 2;
  const int ccol = lane & 15;
#pragma unroll
  for (int fm = 0; fm < 2; ++fm)
#pragma unroll
    for (int r = 0; r < 4; ++r) {
      const int l = m0 + wm * 32 + fm * 16 + crow + r;
      const float c = cvec[bh * L_ + l];
      const float* bap = band + (((size_t)(bh * L_ + l)) << 3);
      const float4 b0v = *(const float4*)bap;
      const float4 b1v = *(const float4*)(bap + 4);
      const float bav[7] = {b0v.x, b0v.y, b0v.z, b0v.w, b1v.x, b1v.y, b1v.z};
#pragma unroll
      for (int fn = 0; fn < 2; ++fn) {
        const floatx4 acc = (fm == 0) ? ((fn == 0) ? acc00 : acc01)
                                      : ((fn == 0) ? acc10 : acc11);
        const int d = wn * 32 + fn * 16 + ccol;
        float corr = 0.f;
#pragma unroll
        for (int u = 0; u < 7; ++u) {
          int j = l - 3 + u;
          const int jc = j < 0 ? 0 : (j > 1023 ? 1023 : j);
          corr = fmaf(bav[u], bf2f(vS[((size_t)bh * S_ + jc) * DH + d]), corr);
        }
        const float val = fmaf(c, acc[r], corr);
        out1[((size_t)(b * L_ + l)) * DMODEL + h * DH + d] = f2bf(val);
      }
    }
}

// ---------------------------------------------------------------------------
extern "C" void kernel_launch(void* const* d_in, const int* in_sizes, int n_in,
                              void* d_out, int out_size, void* d_ws, size_t ws_size,
                              hipStream_t stream) {
  const float* queries = (const float*)d_in[0];
  const float* keys    = (const float*)d_in[1];
  const float* values  = (const float*)d_in[2];
  const float* Wq      = (const float*)d_in[3];
  const float* Wk      = (const float*)d_in[4];
  const float* Wv      = (const float*)d_in[5];
  const float* Wo      = (const float*)d_in[6];

  float* out  = (float*)d_out;                          // (B,L,512) f32
  float* attn = out + (size_t)B_ * L_ * DMODEL;         // (B,H,L,S) f32 (scores->attn)

  char* ws = (char*)d_ws;
  short* xbf  = (short*)(ws);                    // 12 MiB: q,k,v bf16
  short* WT   = (short*)(ws + 12u * 1048576);    //  2 MiB: 4 x W^T bf16
  short* qbf  = (short*)(ws + 14u * 1048576);    //  4 MiB (B,H,L,D)
  short* kbf  = (short*)(ws + 18u * 1048576);    //  4 MiB (B,H,S,D)
  short* vT   = (short*)(ws + 22u * 1048576);    //  4 MiB (B,H,D,S)
  short* vS   = (short*)(ws + 26u * 1048576);    //  4 MiB (B,H,S,D)
  float* pm   = (float*)(ws + 30u * 1048576);    //  4 MiB (L,S) f32
  short* E    = (short*)(ws + 34u * 1048576);    //  2 MiB (L,S) bf16
  float* pmmax= (float*)(ws + 36u * 1048576);    //  4 KiB
  float* pmsum= (float*)(ws + 36u * 1048576 + 4096);        // 4 KiB
  float* cvec = (float*)(ws + 36u * 1048576 + 65536);       // 128 KiB (bh,i)
  float* band = (float*)(ws + 37u * 1048576);    //  1 MiB (bh,i,8) f32
  short* out1 = (short*)(ws + 38u * 1048576);    //  4 MiB (B,L,512) bf16  -> 42 MiB

  const dim3 blk(256);

  // 0) input f32->bf16, weight transpose->bf16
  hipLaunchKernelGGL(cvt_inputs_kernel, dim3(3072), blk, 0, stream,
                     queries, keys, values, xbf);
  hipLaunchKernelGGL(wtrans_kernel, dim3(16, 16, 4), blk, 0, stream,
                     Wq, Wk, Wv, Wo, WT);

  // 1) projections (MFMA)
  const dim3 gProj(DMODEL / 64, (B_ * L_) / 64);        // (8, 64)
  hipLaunchKernelGGL((proj_mfma_kernel<0>), gProj, blk, 0, stream,
                     xbf,           WT,          (void*)qbf, (short*)nullptr, DMODEL);
  hipLaunchKernelGGL((proj_mfma_kernel<0>), gProj, blk, 0, stream,
                     xbf + 2097152, WT + 262144, (void*)kbf, (short*)nullptr, DMODEL);
  hipLaunchKernelGGL((proj_mfma_kernel<3>), gProj, blk, 0, stream,
                     xbf + 4194304, WT + 524288, (void*)vT,  vS,              DMODEL);

  // 2) scores = q k^T / 8 (f32, into attn region of d_out)
  const dim3 gSc(S_ / 64, L_ / 64, NBH);                // (16,16,32)
  hipLaunchKernelGGL(scores_mfma_kernel, gSc, blk, 0, stream, qbf, kbf, attn);

  // 3) path_mean from raw scores (tiled gather)
  hipLaunchKernelGGL(path_mean_kernel, dim3(1024), blk, 0, stream, attn, pm);

  // 4) per-row pm stats + E = exp(pm - max) bf16 (band zeroed)
  hipLaunchKernelGGL(pm_stats_kernel, dim3(L_ / 4), blk, 0, stream,
                     pm, E, pmmax, pmsum);

  // 5) attn rows in place (reads own band scores first), emits c + band attn
  hipLaunchKernelGGL(attn_write_kernel, dim3(L_ / 4, NBH), blk, 0, stream,
                     attn, E, pmmax, pmsum, cvec, band);

  // 6) EV GEMM + band correction -> out1 bf16
  hipLaunchKernelGGL(ev_kernel, dim3(L_ / 64, NBH), blk, 0, stream,
                     E, vT, vS, cvec, band, out1);

  // 7) out = out1 @ W_o (MFMA, f32 out)
  hipLaunchKernelGGL((proj_mfma_kernel<2>), gProj, blk, 0, stream,
                     out1, WT + 786432, (void*)out, (short*)nullptr, DMODEL);
}